// Round 10
// baseline (1381.066 us; speedup 1.0000x reference)
//
#include <hip/hip_runtime.h>
#include <hip/hip_bf16.h>

// ConvGeodesic: f16x3 split-precision MFMA GEMM (256x256xBK64), 4-phase
// pipelined K-loop with counted vmcnt (T3+T4) + setprio (T5), then select.
//   k_ksum:   Ksum = sum_k kernel
//   k_wt:     WT[q=(r,o)][k'=(seg,j,i,n)] f16 hi|hi|lo
//   k_interp: X[row][(j,i,n)] f16 hi|lo — one wave/row, float2 gathers,
//             packed f16x2 stores (256 B/instr coalesced both planes)
//   k_gemm:   256x256 tile, BK=64, 8 waves (2x4). Per K-tile 4 phases
//     (kk, m-half): {ds_read | prefetch-issue | barrier | lgkm0 | 16 MFMA | vmcnt | barrier}.
//     Prefetch t+2 split 6@p3(t) + 2@p0(t+1); vmcnt(8) steady, 6 prologue,
//     2/0 epilogue. B-frags register-cached across m-half phases. XOR swizzle.
//   k_select: per point argmax over 8 norms -> copy winning 128 cols.

typedef _Float16 f16;
typedef _Float16 f16x2 __attribute__((ext_vector_type(2)));
typedef _Float16 f16x8 __attribute__((ext_vector_type(8)));
typedef float f32x4 __attribute__((ext_vector_type(4)));

#define B_   2
#define M_   20000
#define T_   8
#define R_   5
#define NIN  64
#define O_   128
#define K_   4

#define PTS   (B_*M_)      // 40000
#define PTSPAD 40192       // 157*256
#define KSEG  2560         // T_*R_*NIN
#define KPHY  5120         // X cols: [hi | lo]
#define KLOG  7680         // GEMM K: hi*Whi + lo*Whi + hi*Wlo
#define NQ    1024         // T_*O_
#define SCALE 16.0f
#define INVSS (1.0f/(SCALE*SCALE))

#define BM    256
#define BK    64
#define TS    (KLOG/BK)    // 120 K-tiles

__global__ void k_ksum(const float* __restrict__ kern, float* __restrict__ ksum) {
    int i = blockIdx.x * 256 + threadIdx.x;
    const int total = T_ * R_ * O_ * NIN;
    if (i >= total) return;
    float s = 0.f;
#pragma unroll
    for (int k = 0; k < K_; k++) s += kern[k * total + i];
    ksum[i] = s;
}

__global__ void k_wt(const float* __restrict__ ksum, f16* __restrict__ wt) {
    int idx = blockIdx.x * 256 + threadIdx.x;  // over NQ*KSEG
    const int total = NQ * KSEG;
    if (idx >= total) return;
    int q = idx / KSEG;
    int k = idx - q * KSEG;
    int r = q >> 7, o = q & 127;
    int j = k / 320;
    int rem = k - j * 320;
    int i = rem >> 6, n = rem & 63;
    int t = (j + r) & 7;
    float v = SCALE * ksum[((((t * R_ + i) * O_ + o) << 6) + n)];
    f16 hi = (f16)v;
    f16 lo = (f16)(v - (float)hi);
    f16* row = wt + (size_t)q * KLOG;
    row[k] = hi;
    row[k + KSEG] = hi;
    row[k + 2 * KSEG] = lo;
}

// one wave per X row. Per iter: lanes 0-31 cell c, lanes 32-63 cell c+1;
// each lane covers a col-pair. float2 gathers, packed f16x2 stores.
__global__ void k_interp(const float* __restrict__ sig, const float* __restrict__ bw,
                         const int* __restrict__ bi, f16* __restrict__ X,
                         int pt0, int rows_pad) {
    int nwaves = gridDim.x * 4;
    int wav = (blockIdx.x * 256 + threadIdx.x) >> 6;
    int lane = threadIdx.x & 63;
    int half = lane >> 5;          // 0/1: which cell of the pair
    int n0 = (lane & 31) * 2;      // col-pair base
    for (int lr = wav; lr < rows_pad; lr += nwaves) {
        int lru = __builtin_amdgcn_readfirstlane(lr);
        int pt = pt0 + lru;
        f16* rowp = X + (size_t)lru * KPHY;
        if (pt >= PTS) {  // zero-fill pad rows: poison must not reach MFMA
            const f16x2 z = {(f16)0.f, (f16)0.f};
#pragma unroll
            for (int it = 0; it < 20; it++) {
                int col = (2 * it + half) * 64 + n0;
                *(f16x2*)(rowp + col) = z;
                *(f16x2*)(rowp + KSEG + col) = z;
            }
            continue;
        }
        int b = (pt >= M_) ? 1 : 0;
        const float* sb = sig + (size_t)b * M_ * NIN;
        const float* wpb = bw + (size_t)pt * 120;
        const int* ipb = bi + (size_t)pt * 120;
#pragma unroll 4
        for (int it = 0; it < 20; it++) {
            int cell = 2 * it + half;
            int wb = cell * 3;
            float w0 = wpb[wb], w1 = wpb[wb + 1], w2 = wpb[wb + 2];
            int i0 = ipb[wb], i1 = ipb[wb + 1], i2 = ipb[wb + 2];
            float2 s0 = *(const float2*)(sb + (size_t)i0 * NIN + n0);
            float2 s1 = *(const float2*)(sb + (size_t)i1 * NIN + n0);
            float2 s2 = *(const float2*)(sb + (size_t)i2 * NIN + n0);
            float x0 = fmaf(w2, s2.x, fmaf(w1, s1.x, w0 * s0.x)) * SCALE;
            float x1 = fmaf(w2, s2.y, fmaf(w1, s1.y, w0 * s0.y)) * SCALE;
            f16 h0 = (f16)x0, h1 = (f16)x1;
            f16 l0 = (f16)(x0 - (float)h0), l1 = (f16)(x1 - (float)h1);
            int col = cell * 64 + n0;
            f16x2 hv = {h0, h1};
            f16x2 lv = {l0, l1};
            *(f16x2*)(rowp + col) = hv;
            *(f16x2*)(rowp + KSEG + col) = lv;
        }
    }
}

#define SBAR()  __builtin_amdgcn_s_barrier()
#define SCHED() __builtin_amdgcn_sched_barrier(0)
#define LGKM0() asm volatile("s_waitcnt lgkmcnt(0)" ::: "memory")

__global__ __launch_bounds__(512, 1) void k_gemm(
    const f16* __restrict__ X, const f16* __restrict__ WT,
    float* __restrict__ conv, float* __restrict__ norms, int pt0) {
    // dbuf LDS: As/Bs [2][256][64] halfs = 64 KB each; sred 4 KB. 132 KB.
    __shared__ __align__(16) f16 As[2][256 * 64];
    __shared__ __align__(16) f16 Bs[2][256 * 64];
    __shared__ float sred[4][256];

    // bijective XCD-chunked swizzle (m204)
    int nwg = gridDim.x;
    int bq = nwg >> 3, br_ = nwg & 7;
    int xcd = blockIdx.x & 7, slot = blockIdx.x >> 3;
    int logical = (xcd < br_ ? xcd * (bq + 1) : br_ * (bq + 1) + (xcd - br_) * bq) + slot;
    int mblk = logical >> 2, nb = logical & 3;
    const int m0 = mblk * BM;
    const int n0 = nb * 256;

    const int t = threadIdx.x;
    const int w = t >> 6, lane = t & 63;
    const int wr = w >> 2, wc = w & 3;     // 2m x 4n waves; wave tile 128x64
    const int lq = lane >> 4, lr16 = lane & 15;
    const int fr = lr16 & 7;               // read-side swizzle bits
    const int src_off = (((t & 7) ^ ((t >> 3) & 7)) << 3);  // staging pre-swizzle

    f32x4 acc[8][4];
#pragma unroll
    for (int a = 0; a < 8; a++)
#pragma unroll
        for (int b = 0; b < 4; b++) acc[a][b] = (f32x4){0.f, 0.f, 0.f, 0.f};

    const f16* pA = X + (size_t)(m0 + (t >> 3)) * KPHY + src_off;
    const f16* pB = WT + (size_t)(n0 + (t >> 3)) * KLOG + src_off;

    // A/B quarter Q (rows Q*64..Q*64+63) of K-tile KT -> buffer BUF
#define GLA(Q, BUF, KT) do {                                                          \
        int k0_ = (KT) * BK;                                                          \
        int kA_ = k0_ - ((k0_ >= KPHY) ? KPHY : 0); /* seg2 re-reads x_hi */          \
        __builtin_amdgcn_global_load_lds(                                             \
            (const __attribute__((address_space(1))) void*)(pA + kA_ + (size_t)(Q) * 64 * KPHY), \
            (__attribute__((address_space(3))) void*)(&As[BUF][(Q) * 4096 + t * 8]), 16, 0, 0); \
    } while (0)
#define GLB(Q, BUF, KT) do {                                                          \
        int k0_ = (KT) * BK;                                                          \
        __builtin_amdgcn_global_load_lds(                                             \
            (const __attribute__((address_space(1))) void*)(pB + k0_ + (size_t)(Q) * 64 * KLOG), \
            (__attribute__((address_space(3))) void*)(&Bs[BUF][(Q) * 4096 + t * 8]), 16, 0, 0); \
    } while (0)

    // prologue: tile0 full (8), tile1 first-6 (A-Q0,Q2 + B-all)
    GLA(0, 0, 0); GLA(1, 0, 0); GLA(2, 0, 0); GLA(3, 0, 0);
    GLB(0, 0, 0); GLB(1, 0, 0); GLB(2, 0, 0); GLB(3, 0, 0);
    GLA(0, 1, 1); GLA(2, 1, 1);
    GLB(0, 1, 1); GLB(1, 1, 1); GLB(2, 1, 1); GLB(3, 1, 1);
    asm volatile("s_waitcnt vmcnt(6)" ::: "memory");  // ALL of tile0's 8 landed
    SBAR(); SCHED();

    f16x8 af[4], bf[4], bg[4];
    for (int kt = 0; kt < TS; ++kt) {
        const int b = kt & 1;
        const f16* Ac = &As[b][0];
        const f16* Bc = &Bs[b][0];
        const int cho0 = (lq ^ fr) << 3;          // kk=0 chunks
        const int cho1 = ((4 + lq) ^ fr) << 3;    // kk=1 chunks

        // ---- p0: (kk0, mh0) — reads A-Q(wr*2), B-all(kk0)
#pragma unroll
        for (int mf = 0; mf < 4; mf++)
            af[mf] = *(const f16x8*)(Ac + (wr * 128 + mf * 16 + lr16) * 64 + cho0);
#pragma unroll
        for (int nf = 0; nf < 4; nf++)
            bf[nf] = *(const f16x8*)(Bc + (wc * 64 + nf * 16 + lr16) * 64 + cho0);
        if (kt + 1 < TS) { GLA(1, b ^ 1, kt + 1); GLA(3, b ^ 1, kt + 1); }
        SBAR(); SCHED();
        LGKM0(); SCHED();
        __builtin_amdgcn_s_setprio(1);
#pragma unroll
        for (int mf = 0; mf < 4; mf++)
#pragma unroll
            for (int nf = 0; nf < 4; nf++)
                acc[mf][nf] = __builtin_amdgcn_mfma_f32_16x16x32_f16(af[mf], bf[nf], acc[mf][nf], 0, 0, 0);
        __builtin_amdgcn_s_setprio(0); SCHED();
        if (kt < TS - 1) asm volatile("s_waitcnt vmcnt(8)" ::: "memory");  // L(kt) landed
        else             asm volatile("s_waitcnt vmcnt(0)" ::: "memory");
        SBAR(); SCHED();

        // ---- p1: (kk0, mh1) — reads A-Q(wr*2+1); B reused
#pragma unroll
        for (int mf = 0; mf < 4; mf++)
            af[mf] = *(const f16x8*)(Ac + (wr * 128 + 64 + mf * 16 + lr16) * 64 + cho0);
        SBAR(); SCHED();
        LGKM0(); SCHED();
        __builtin_amdgcn_s_setprio(1);
#pragma unroll
        for (int mf = 0; mf < 4; mf++)
#pragma unroll
            for (int nf = 0; nf < 4; nf++)
                acc[4 + mf][nf] = __builtin_amdgcn_mfma_f32_16x16x32_f16(af[mf], bf[nf], acc[4 + mf][nf], 0, 0, 0);
        __builtin_amdgcn_s_setprio(0); SCHED();
        SBAR(); SCHED();

        // ---- p2: (kk1, mh0) — reads A-Q(wr*2) kk1, B-all(kk1)
#pragma unroll
        for (int mf = 0; mf < 4; mf++)
            af[mf] = *(const f16x8*)(Ac + (wr * 128 + mf * 16 + lr16) * 64 + cho1);
#pragma unroll
        for (int nf = 0; nf < 4; nf++)
            bg[nf] = *(const f16x8*)(Bc + (wc * 64 + nf * 16 + lr16) * 64 + cho1);
        SBAR(); SCHED();
        LGKM0(); SCHED();
        __builtin_amdgcn_s_setprio(1);
#pragma unroll
        for (int mf = 0; mf < 4; mf++)
#pragma unroll
            for (int nf = 0; nf < 4; nf++)
                acc[mf][nf] = __builtin_amdgcn_mfma_f32_16x16x32_f16(af[mf], bg[nf], acc[mf][nf], 0, 0, 0);
        __builtin_amdgcn_s_setprio(0); SCHED();
        SBAR(); SCHED();

        // ---- p3: (kk1, mh1) — reads A-Q(wr*2+1) kk1; issue tile kt+2 first-6
#pragma unroll
        for (int mf = 0; mf < 4; mf++)
            af[mf] = *(const f16x8*)(Ac + (wr * 128 + 64 + mf * 16 + lr16) * 64 + cho1);
        if (kt + 2 < TS) {
            GLA(0, b, kt + 2); GLA(2, b, kt + 2);
            GLB(0, b, kt + 2); GLB(1, b, kt + 2); GLB(2, b, kt + 2); GLB(3, b, kt + 2);
        }
        SBAR(); SCHED();
        LGKM0(); SCHED();
        __builtin_amdgcn_s_setprio(1);
#pragma unroll
        for (int mf = 0; mf < 4; mf++)
#pragma unroll
            for (int nf = 0; nf < 4; nf++)
                acc[4 + mf][nf] = __builtin_amdgcn_mfma_f32_16x16x32_f16(af[mf], bg[nf], acc[4 + mf][nf], 0, 0, 0);
        __builtin_amdgcn_s_setprio(0); SCHED();
        if (kt < TS - 2)       asm volatile("s_waitcnt vmcnt(8)" ::: "memory");  // F(kt+1) landed
        else if (kt == TS - 2) asm volatile("s_waitcnt vmcnt(2)" ::: "memory");
        SBAR(); SCHED();
    }
#undef GLA
#undef GLB

    // epilogue: relu -> conv store (post-relu) + per-row norms for 2 rotations
#pragma unroll
    for (int mf = 0; mf < 8; mf++)
#pragma unroll
        for (int nf = 0; nf < 4; nf++)
#pragma unroll
            for (int jj = 0; jj < 4; jj++)
                acc[mf][nf][jj] = fmaxf(acc[mf][nf][jj], 0.f);

#pragma unroll
    for (int mf = 0; mf < 8; mf++)
#pragma unroll
        for (int jj = 0; jj < 4; jj++) {
            int rowl = wr * 128 + mf * 16 + lq * 4 + jj;
            float s = 0.f;
#pragma unroll
            for (int nf = 0; nf < 4; nf++) {
                float v = acc[mf][nf][jj];
                s = fmaf(v, v, s);
                conv[(size_t)(m0 + rowl) * NQ + n0 + wc * 64 + nf * 16 + lr16] = v;
            }
            s += __shfl_xor(s, 1, 64);
            s += __shfl_xor(s, 2, 64);
            s += __shfl_xor(s, 4, 64);
            s += __shfl_xor(s, 8, 64);
            if (lr16 == 0) sred[wc][rowl] = s;
        }
    __syncthreads();
    if (t < 256) {
        float e = sred[0][t] + sred[1][t];   // rotation 2*nb
        float o = sred[2][t] + sred[3][t];   // rotation 2*nb+1
        float2* np = (float2*)&norms[(size_t)(pt0 + m0 + t) * 8 + nb * 2];
        *np = make_float2(e, o);
    }
}

__global__ void k_select(const float* __restrict__ conv, const float* __restrict__ norms,
                         float* __restrict__ out, int pt0, int rows) {
    int nwaves = gridDim.x * 4;
    int wav = (blockIdx.x * 256 + threadIdx.x) >> 6;
    int lane = threadIdx.x & 63;
    for (int task = wav; task < rows; task += nwaves) {
        int tu = __builtin_amdgcn_readfirstlane(task);
        int pt = pt0 + tu;
        if (pt >= PTS) continue;
        const float* np = norms + (size_t)pt * 8;
        float bs = np[0];
        int br = 0;
#pragma unroll
        for (int r = 1; r < 8; r++) {
            float v = np[r];
            if (v > bs) { bs = v; br = r; }  // strict >: first max = argmax
        }
        const float2 v = *(const float2*)&conv[(size_t)tu * NQ + br * 128 + lane * 2];
        float2 o;
        o.x = v.x * INVSS;
        o.y = v.y * INVSS;
        *(float2*)&out[(size_t)pt * O_ + lane * 2] = o;
    }
}

extern "C" void kernel_launch(void* const* d_in, const int* in_sizes, int n_in,
                              void* d_out, int out_size, void* d_ws, size_t ws_size,
                              hipStream_t stream) {
    const float* sig = (const float*)d_in[0];
    const float* bw = (const float*)d_in[1];
    const int* bi = (const int*)d_in[2];
    const float* kern = (const float*)d_in[3];
    float* out = (float*)d_out;
    char* ws = (char*)d_ws;

    const size_t sz_ksum = (size_t)T_ * R_ * O_ * NIN * sizeof(float);  // 1.31 MB
    const size_t sz_wt = (size_t)NQ * KLOG * sizeof(f16);               // 15.7 MB
    const size_t sz_norms = (size_t)PTSPAD * 8 * sizeof(float);         // 1.29 MB
    float* ksum = (float*)ws;
    f16* WT = (f16*)(ws + sz_ksum);
    float* norms = (float*)(ws + sz_ksum + sz_wt);
    char* dyn = ws + sz_ksum + sz_wt + sz_norms;

    size_t persist = sz_ksum + sz_wt + sz_norms;
    size_t avail = (ws_size > persist) ? (ws_size - persist) : 0;
    // per-row: X 10240 B + conv 4096 B
    long maxrows = (long)(avail / (size_t)(KPHY * 2 + NQ * 4));
    int chunk = (int)((maxrows / BM) * BM);
    if (chunk < BM) chunk = BM;
    if (chunk > PTSPAD) chunk = PTSPAD;

    f16* X = (f16*)dyn;
    float* conv = (float*)(dyn + (size_t)chunk * KPHY * sizeof(f16));

    k_ksum<<<(T_ * R_ * O_ * NIN + 255) / 256, 256, 0, stream>>>(kern, ksum);
    k_wt<<<(NQ * KSEG + 255) / 256, 256, 0, stream>>>(ksum, WT);

    for (int pt0 = 0; pt0 < PTS; pt0 += chunk) {
        int rem = PTS - pt0;
        int rows = (rem < chunk) ? rem : chunk;
        int rows_pad = (rows + BM - 1) & ~(BM - 1);
        k_interp<<<4096, 256, 0, stream>>>(sig, bw, bi, X, pt0, rows_pad);
        k_gemm<<<(rows_pad / BM) * 4, 512, 0, stream>>>(X, WT, conv, norms, pt0);
        k_select<<<2048, 256, 0, stream>>>(conv, norms, out, pt0, rows);
    }
}